// Round 5
// baseline (2828.962 us; speedup 1.0000x reference)
//
#include <hip/hip_runtime.h>

// ---------------------------------------------------------------------------
// GraphSAGE layer — ROUND 5: fp32 contract (reference dtypes are float32;
// the "bf16" in the test label is hard-coded and carries no information),
// single kernel symbol matching the original stub name, phase-dispatched.
//
//   phase 0: agg  = (adj>0)@x / max(deg,1)            -> d_out (temp, fp32)
//   phase 1: comb[:, 0:512]   = x   @ W_self + b_self -> ws
//   phase 2: comb[:, 512:1024]= agg @ W_nb   + b_nb   -> ws
//   phase 3: out  = relu(comb @ W_comb + b_comb)      -> d_out (final)
//
// All phases: 32x32 tile GEMM, 256 threads, 2x2 micro-tile, LDS staging.
// Canary: kernel_launch first memsets d_out to byte 0x40 (fp32 ~= 3.006).
// If the final result reads back ~3.006 everywhere, kernel_launch ran but
// device kernels did not; if exactly 1.359375 again, kernel_launch never ran.
// ---------------------------------------------------------------------------

__global__ void GraphSAGELayer_773094114149_kernel(
    int phase,
    const float* x, const int* adj,
    const float* Wself, const float* bself,
    const float* Wnb, const float* bnb,
    const float* Wcomb, const float* bcomb,
    float* outp, float* comb)
{
  __shared__ float As[32][33];
  __shared__ float Bs[32][33];
  __shared__ float degp[32][8];
  __shared__ float deg[32];

  const int t   = threadIdx.x;
  const int tx  = t & 15;
  const int ty  = t >> 4;
  const int lr  = t >> 3;        // 0..31  staging row
  const int lc8 = t & 7;         // 0..7   stager id within row
  const int lc  = lc8 * 4;       // 0,4,...,28
  const int rowBase = blockIdx.y * 32;
  const int colBase = blockIdx.x * 32;

  // ---- per-phase operand selection (wave-uniform) ----
  const float* A;  const float* B;  const float* bias;  float* C;
  int lda, ldb, ldc, K;
  if (phase == 0) {
    A = 0;     lda = 0;    B = x;     ldb = 512; bias = 0;     C = outp;       ldc = 512;  K = 8192;
  } else if (phase == 1) {
    A = x;     lda = 512;  B = Wself; ldb = 512; bias = bself; C = comb;       ldc = 1024; K = 512;
  } else if (phase == 2) {
    A = outp;  lda = 512;  B = Wnb;   ldb = 512; bias = bnb;   C = comb + 512; ldc = 1024; K = 512;
  } else {
    A = comb;  lda = 1024; B = Wcomb; ldb = 512; bias = bcomb; C = outp;       ldc = 512;  K = 1024;
  }

  float acc00 = 0.0f, acc01 = 0.0f, acc10 = 0.0f, acc11 = 0.0f;
  float dsum = 0.0f;   // phase 0: partial degree of row (rowBase+lr)

  for (int k0 = 0; k0 < K; k0 += 32) {
    if (phase == 0) {
      for (int q = 0; q < 4; ++q) {
        float m = (adj[(size_t)(rowBase + lr) * 8192 + (k0 + lc + q)] > 0) ? 1.0f : 0.0f;
        As[lr][lc + q] = m;
        dsum += m;
      }
    } else {
      for (int q = 0; q < 4; ++q)
        As[lr][lc + q] = A[(size_t)(rowBase + lr) * lda + (k0 + lc + q)];
    }
    for (int q = 0; q < 4; ++q)
      Bs[lr][lc + q] = B[(size_t)(k0 + lr) * ldb + (colBase + lc + q)];
    __syncthreads();

    for (int kk = 0; kk < 32; ++kk) {
      float a0 = As[ty * 2][kk];
      float a1 = As[ty * 2 + 1][kk];
      float b0 = Bs[kk][tx * 2];
      float b1 = Bs[kk][tx * 2 + 1];
      acc00 += a0 * b0;
      acc01 += a0 * b1;
      acc10 += a1 * b0;
      acc11 += a1 * b1;
    }
    __syncthreads();
  }

  const int r0 = rowBase + ty * 2;
  const int c0 = colBase + tx * 2;

  if (phase == 0) {
    degp[lr][lc8] = dsum;
    __syncthreads();
    if (t < 32) {
      float s = 0.0f;
      for (int q = 0; q < 8; ++q) s += degp[t][q];
      deg[t] = fmaxf(s, 1.0f);
    }
    __syncthreads();
    float i0 = 1.0f / deg[ty * 2];
    float i1 = 1.0f / deg[ty * 2 + 1];
    C[(size_t)r0 * ldc + c0]           = acc00 * i0;
    C[(size_t)r0 * ldc + c0 + 1]       = acc01 * i0;
    C[(size_t)(r0 + 1) * ldc + c0]     = acc10 * i1;
    C[(size_t)(r0 + 1) * ldc + c0 + 1] = acc11 * i1;
  } else {
    float b0 = bias[c0];
    float b1 = bias[c0 + 1];
    float v00 = acc00 + b0;
    float v01 = acc01 + b1;
    float v10 = acc10 + b0;
    float v11 = acc11 + b1;
    if (phase == 3) {
      v00 = fmaxf(v00, 0.0f);
      v01 = fmaxf(v01, 0.0f);
      v10 = fmaxf(v10, 0.0f);
      v11 = fmaxf(v11, 0.0f);
    }
    C[(size_t)r0 * ldc + c0]           = v00;
    C[(size_t)r0 * ldc + c0 + 1]       = v01;
    C[(size_t)(r0 + 1) * ldc + c0]     = v10;
    C[(size_t)(r0 + 1) * ldc + c0 + 1] = v11;
  }
}

// ---------------------------------------------------------------------------
extern "C" void kernel_launch(void* const* d_in, const int* in_sizes, int n_in,
                              void* d_out, int out_size, void* d_ws, size_t ws_size,
                              hipStream_t stream) {
  (void)in_sizes; (void)n_in; (void)ws_size;

  const float* x     = (const float*)d_in[0];
  const int*   adj   = (const int*)d_in[1];
  const float* Wself = (const float*)d_in[2];
  const float* bself = (const float*)d_in[3];
  const float* Wnb   = (const float*)d_in[4];
  const float* bnb   = (const float*)d_in[5];
  const float* Wcomb = (const float*)d_in[6];
  const float* bcomb = (const float*)d_in[7];

  float* out  = (float*)d_out;   // 8192*512 fp32 (16 MB)
  float* comb = (float*)d_ws;    // 8192*1024 fp32 (32 MB)

  // Execution canary: fp32 pattern 0x40404040 ~= 3.006. Overwritten by the
  // phases below when kernels execute; survives if kernel launches fail.
  hipMemsetAsync(d_out, 0x40, (size_t)out_size * sizeof(float), stream);

  const dim3 grid(16, 256);   // N/32 = 16, M/32 = 256
  for (int phase = 0; phase < 4; ++phase) {
    GraphSAGELayer_773094114149_kernel<<<grid, 256, 0, stream>>>(
        phase, x, adj, Wself, bself, Wnb, bnb, Wcomb, bcomb, out, comb);
  }
}

// Round 6
// 605.039 us; speedup vs baseline: 4.6757x; 4.6757x over previous
//
#include <hip/hip_runtime.h>

// ---------------------------------------------------------------------------
// GraphSAGE layer — ROUND 6: single-kernel (harness tolerates only one
// __global__ symbol — R1-R4 multi-kernel builds never ran; R5 single ran),
// fp32 I/O contract, MFMA bf16 core.
//
//   phase 0: x fp32 -> xbf (bf16 row-major) + xT (bf16 transposed [512][8192])
//   phase 1: Wt[n][k] = fused (W_self@Wc1 | W_nb@Wc2) bf16; cbias fp32
//   phase 2: agg = (adj>0)@x / max(deg,1)   via mfma_f32_16x16x32_bf16
//   phase 3: out = relu([xbf|agg] @ Wt^T + cbias) -> fp32 d_out
//
// exactness: out = relu(x@(Ws@Wc1) + agg@(Wnb@Wc2) + (bs@Wc1+bn@Wc2+bc))
// is algebraically identical to the reference; bf16 rounding ~1e-2 << 2.7e-2.
// ---------------------------------------------------------------------------

using short8 = __attribute__((ext_vector_type(8))) short;   // 8 bf16 (4 VGPRs)
using f32x4  = __attribute__((ext_vector_type(4))) float;   // MFMA acc

typedef unsigned short U16;
typedef unsigned int   U32;

__device__ __forceinline__ U16 f2bf(float f) {
  U32 u = __float_as_uint(f);
  u = (u + 0x7fffu + ((u >> 16) & 1u)) >> 16;   // RNE
  return (U16)u;
}
__device__ __forceinline__ U32 pack2bf(float a, float b) {
  return (U32)f2bf(a) | ((U32)f2bf(b) << 16);
}

__global__ void GraphSAGELayer_773094114149_kernel(
    int phase,
    const float* __restrict__ x,     const int* __restrict__ adj,
    const float* __restrict__ Wself, const float* __restrict__ bself,
    const float* __restrict__ Wnb,   const float* __restrict__ bnb,
    const float* __restrict__ Wcomb, const float* __restrict__ bcomb,
    U16* __restrict__ xT, U16* __restrict__ xbf, U16* __restrict__ aggp,
    U16* __restrict__ Wt, float* __restrict__ cbias, float* __restrict__ outp)
{
  __shared__ __align__(16) unsigned char smem[27648];
  const int tid = threadIdx.x;

  // =========================================================================
  // phase 0: convert + transpose. grid (8, 128), 256 thr. 64x64 tiles.
  // =========================================================================
  if (phase == 0) {
    U16* tl = (U16*)smem;                       // [64][72] (144 B rows)
    const int n0 = blockIdx.x * 64;
    const int m0 = blockIdx.y * 64;
    const int r  = tid >> 2;
    const int cq = (tid & 3) * 16;

    const float* src = x + (size_t)(m0 + r) * 512 + n0 + cq;
    float v[16];
    for (int i = 0; i < 16; i += 4) {
      float4 f = *(const float4*)(src + i);
      v[i] = f.x; v[i+1] = f.y; v[i+2] = f.z; v[i+3] = f.w;
    }
    U32 pk[8];
    for (int i = 0; i < 8; ++i) pk[i] = pack2bf(v[2*i], v[2*i+1]);

    U16* dst = xbf + (size_t)(m0 + r) * 512 + n0 + cq;
    *(uint4*)dst       = make_uint4(pk[0], pk[1], pk[2], pk[3]);
    *(uint4*)(dst + 8) = make_uint4(pk[4], pk[5], pk[6], pk[7]);

    for (int i = 0; i < 8; ++i) {
      tl[(cq + 2*i)     * 72 + r] = (U16)(pk[i] & 0xffffu);
      tl[(cq + 2*i + 1) * 72 + r] = (U16)(pk[i] >> 16);
    }
    __syncthreads();
    const int c2 = tid >> 2;
    const int mq = (tid & 3) * 16;
    uint4 o0 = *(const uint4*)&tl[c2 * 72 + mq];
    uint4 o1 = *(const uint4*)&tl[c2 * 72 + mq + 8];
    U16* dT = xT + (size_t)(n0 + c2) * 8192 + m0 + mq;
    *(uint4*)dT       = o0;
    *(uint4*)(dT + 8) = o1;
    return;
  }

  // =========================================================================
  // phase 1: fused weights + bias. grid (258), 256 thr.
  //  blocks 0..255: half = b>>7, k0 = (b&127)*4:
  //    Wt[n][half*512+k0+q] = sum_j Wsrc[k0+q][j] * Wcomb[half*512+j][n]
  //  blocks 256,257: cbias[n] = bself@Wc1 + bnb@Wc2 + bcomb
  // =========================================================================
  if (phase == 1) {
    if (blockIdx.x >= 256) {
      int n = (int)(blockIdx.x - 256) * 256 + tid;
      float acc = bcomb[n];
      for (int j = 0; j < 512; ++j) {
        acc += bself[j] * Wcomb[(size_t)j * 512 + n];
        acc += bnb[j]   * Wcomb[(size_t)(512 + j) * 512 + n];
      }
      cbias[n] = acc;
      return;
    }
    const int half = blockIdx.x >> 7;
    const int k0   = (blockIdx.x & 127) * 4;
    const float* Wsrc = half ? Wnb : Wself;
    const int woff = half * 512;

    float* wsf = (float*)smem;                  // [4][512]
    {
      int idx = tid * 8;                        // 8 consecutive floats
      *(float4*)&wsf[idx]     = *(const float4*)&Wsrc[(size_t)(k0 + (idx >> 9)) * 512 + (idx & 511)];
      *(float4*)&wsf[idx + 4] = *(const float4*)&Wsrc[(size_t)(k0 + ((idx+4) >> 9)) * 512 + ((idx+4) & 511)];
    }
    __syncthreads();

    float a[8] = {0,0,0,0,0,0,0,0};
    for (int j = 0; j < 512; ++j) {
      float wc0 = Wcomb[(size_t)(woff + j) * 512 + tid];
      float wc1 = Wcomb[(size_t)(woff + j) * 512 + tid + 256];
      float s0 = wsf[j], s1 = wsf[512 + j], s2 = wsf[1024 + j], s3 = wsf[1536 + j];
      a[0] += s0 * wc0;  a[4] += s0 * wc1;
      a[1] += s1 * wc0;  a[5] += s1 * wc1;
      a[2] += s2 * wc0;  a[6] += s2 * wc1;
      a[3] += s3 * wc0;  a[7] += s3 * wc1;
    }
    U16* w0 = Wt + (size_t)tid * 1024 + woff + k0;
    U16* w1 = Wt + (size_t)(tid + 256) * 1024 + woff + k0;
    for (int q = 0; q < 4; ++q) { w0[q] = f2bf(a[q]); w1[q] = f2bf(a[4 + q]); }
    return;
  }

  // ---- common MFMA-phase lane decomposition ----
  const int lane = tid & 63;
  const int wave = tid >> 6;
  const int wm = (wave & 1) * 32;
  const int wn = (wave >> 1) * 64;
  const int nBase = blockIdx.x * 128;
  const int mBase = blockIdx.y * 64;

  // =========================================================================
  // phase 2: agg = (adj>0)@x / max(deg,1). grid (4,128), 256 thr.
  // BM=64 BN=128 BK=64. A: adj int4 loads -> {0,1} pack -> bf16 LDS (144B rows)
  // B: xT uint4 loads -> XOR-chunk-swizzled LDS (128B rows). Manual pipeline.
  // =========================================================================
  if (phase == 2) {
    U16* As = (U16*)smem;                       // [64][72]
    U16* Bs = (U16*)(smem + 9216);              // [128][64] swizzled chunks
    float* degp = (float*)(smem + 9216 + 16384);  // [64][4]
    float* degs = degp + 256;                     // [64]

    const int arow = tid >> 2;
    const int* aptr = adj + (size_t)(mBase + arow) * 8192 + (tid & 3) * 16;
    U16* awr = &As[arow * 72 + (tid & 3) * 16];

    const U16* bgp[4]; U16* blp[4];
    for (int i = 0; i < 4; ++i) {
      int c  = i * 256 + tid;
      int nr = c >> 3;
      int gc = c & 7;
      bgp[i] = xT + (size_t)(nBase + nr) * 8192 + gc * 8;
      blp[i] = &Bs[nr * 64 + ((gc ^ (nr & 7)) * 8)];
    }

    f32x4 acc[2][4];
    for (int a = 0; a < 2; ++a)
      for (int b = 0; b < 4; ++b) acc[a][b] = (f32x4){0.f, 0.f, 0.f, 0.f};

    U32 degAcc = 0;

    int4 a0 = ((const int4*)aptr)[0];
    int4 a1 = ((const int4*)aptr)[1];
    int4 a2 = ((const int4*)aptr)[2];
    int4 a3 = ((const int4*)aptr)[3];
    uint4 bv0 = *(const uint4*)(bgp[0]);
    uint4 bv1 = *(const uint4*)(bgp[1]);
    uint4 bv2 = *(const uint4*)(bgp[2]);
    uint4 bv3 = *(const uint4*)(bgp[3]);

    for (int it = 0; it < 128; ++it) {
      __syncthreads();   // previous tile fully consumed

      *(uint4*)blp[0] = bv0;
      *(uint4*)blp[1] = bv1;
      *(uint4*)blp[2] = bv2;
      *(uint4*)blp[3] = bv3;

      U32 p0 = (U32)a0.x | ((U32)a0.y << 16);
      U32 p1 = (U32)a0.z | ((U32)a0.w << 16);
      U32 p2 = (U32)a1.x | ((U32)a1.y << 16);
      U32 p3 = (U32)a1.z | ((U32)a1.w << 16);
      U32 p4 = (U32)a2.x | ((U32)a2.y << 16);
      U32 p5 = (U32)a2.z | ((U32)a2.w << 16);
      U32 p6 = (U32)a3.x | ((U32)a3.y << 16);
      U32 p7 = (U32)a3.z | ((U32)a3.w << 16);
      degAcc += p0 + p1 + p2 + p3 + p4 + p5 + p6 + p7;
      const U32 ONE = 0x3F80u;   // {0,1} -> bf16 {0, 1.0} per 16-bit field
      *(uint4*)awr       = make_uint4(p0 * ONE, p1 * ONE, p2 * ONE, p3 * ONE);
      *(uint4*)(awr + 8) = make_uint4(p4 * ONE, p5 * ONE, p6 * ONE, p7 * ONE);

      __syncthreads();   // tile ready

      if (it + 1 < 128) {
        const int k1 = (it + 1) * 64;
        aptr += 64;
        a0 = ((const int4*)aptr)[0];
        a1 = ((const int4*)aptr)[1];
        a2 = ((const int4*)aptr)[2];
        a3 = ((const int4*)aptr)[3];
        bv0 = *(const uint4*)(bgp[0] + k1);
        bv1 = *(const uint4*)(bgp[1] + k1);
        bv2 = *(const uint4*)(bgp[2] + k1);
        bv3 = *(const uint4*)(bgp[3] + k1);
      }

      for (int s = 0; s < 2; ++s) {
        short8 af[2], bfr[4];
        const int kb = s * 64 + ((lane >> 4) * 16);   // byte offset in A row
        for (int tm = 0; tm < 2; ++tm) {
          int m = wm + tm * 16 + (lane & 15);
          af[tm] = *(const short8*)((const char*)As + m * 144 + kb);
        }
        const int g = s * 4 + (lane >> 4);
        for (int tn = 0; tn < 4; ++tn) {
          int n = wn + tn * 16 + (lane & 15);
          bfr[tn] = *(const short8*)((const char*)Bs + n * 128 + ((g ^ (n & 7)) * 16));
        }
        for (int tm = 0; tm < 2; ++tm)
          for (int tn = 0; tn < 4; ++tn)
            acc[tm][tn] = __builtin_amdgcn_mfma_f32_16x16x32_bf16(
                af[tm], bfr[tn], acc[tm][tn], 0, 0, 0);
      }
    }

    int cnt = (int)((degAcc & 0xffffu) + (degAcc >> 16));
    degp[arow * 4 + (tid & 3)] = (float)cnt;
    __syncthreads();
    if (tid < 64)
      degs[tid] = fmaxf(degp[tid*4] + degp[tid*4+1] + degp[tid*4+2] + degp[tid*4+3], 1.0f);
    __syncthreads();

    for (int tm = 0; tm < 2; ++tm) {
      int rb = wm + tm * 16 + ((lane >> 4) * 4);
      for (int r = 0; r < 4; ++r) {
        float inv = 1.0f / degs[rb + r];
        for (int tn = 0; tn < 4; ++tn) {
          int n = nBase + wn + tn * 16 + (lane & 15);
          aggp[(size_t)(mBase + rb + r) * 512 + n] = f2bf(acc[tm][tn][r] * inv);
        }
      }
    }
    return;
  }

  // =========================================================================
  // phase 3: out = relu([xbf|agg] @ Wt^T + cbias). grid (4,128), 256 thr.
  // K = 1024. Both operands bf16, XOR-chunk-swizzled LDS, manual pipeline.
  // =========================================================================
  {
    U16* As2 = (U16*)smem;                      // [64][64]  (128 B rows)
    U16* Bs2 = (U16*)(smem + 8192);             // [128][64] (128 B rows)

    size_t arowoff[2]; U16* alp[2];
    for (int i = 0; i < 2; ++i) {
      int c  = i * 256 + tid;
      int mr = c >> 3;
      int gc = c & 7;
      arowoff[i] = (size_t)(mBase + mr) * 512 + gc * 8;
      alp[i] = &As2[mr * 64 + ((gc ^ (mr & 7)) * 8)];
    }
    const U16* bgp[4]; U16* blp[4];
    for (int i = 0; i < 4; ++i) {
      int c  = i * 256 + tid;
      int nr = c >> 3;
      int gc = c & 7;
      bgp[i] = Wt + (size_t)(nBase + nr) * 1024 + gc * 8;
      blp[i] = &Bs2[nr * 64 + ((gc ^ (nr & 7)) * 8)];
    }

    f32x4 acc[2][4];
    for (int a = 0; a < 2; ++a)
      for (int b = 0; b < 4; ++b) acc[a][b] = (f32x4){0.f, 0.f, 0.f, 0.f};

    uint4 av0 = *(const uint4*)(xbf + arowoff[0]);
    uint4 av1 = *(const uint4*)(xbf + arowoff[1]);
    uint4 bv0 = *(const uint4*)(bgp[0]);
    uint4 bv1 = *(const uint4*)(bgp[1]);
    uint4 bv2 = *(const uint4*)(bgp[2]);
    uint4 bv3 = *(const uint4*)(bgp[3]);

    for (int it = 0; it < 16; ++it) {
      __syncthreads();
      *(uint4*)alp[0] = av0;
      *(uint4*)alp[1] = av1;
      *(uint4*)blp[0] = bv0;
      *(uint4*)blp[1] = bv1;
      *(uint4*)blp[2] = bv2;
      *(uint4*)blp[3] = bv3;
      __syncthreads();

      if (it + 1 < 16) {
        const int k1 = (it + 1) * 64;
        const U16* ab = (k1 < 512 ? xbf : aggp) + (k1 & 511);
        av0 = *(const uint4*)(ab + arowoff[0]);
        av1 = *(const uint4*)(ab + arowoff[1]);
        bv0 = *(const uint4*)(bgp[0] + k1);
        bv1 = *(const uint4*)(bgp[1] + k1);
        bv2 = *(const uint4*)(bgp[2] + k1);
        bv3 = *(const uint4*)(bgp[3] + k1);
      }

      for (int s = 0; s < 2; ++s) {
        short8 af[2], bfr[4];
        const int g = s * 4 + (lane >> 4);
        for (int tm = 0; tm < 2; ++tm) {
          int m = wm + tm * 16 + (lane & 15);
          af[tm] = *(const short8*)((const char*)As2 + m * 128 + ((g ^ (m & 7)) * 16));
        }
        for (int tn = 0; tn < 4; ++tn) {
          int n = wn + tn * 16 + (lane & 15);
          bfr[tn] = *(const short8*)((const char*)Bs2 + n * 128 + ((g ^ (n & 7)) * 16));
        }
        for (int tm = 0; tm < 2; ++tm)
          for (int tn = 0; tn < 4; ++tn)
            acc[tm][tn] = __builtin_amdgcn_mfma_f32_16x16x32_bf16(
                af[tm], bfr[tn], acc[tm][tn], 0, 0, 0);
      }
    }

    float bias[4];
    for (int tn = 0; tn < 4; ++tn)
      bias[tn] = cbias[nBase + wn + tn * 16 + (lane & 15)];

    for (int tm = 0; tm < 2; ++tm) {
      int rb = wm + tm * 16 + ((lane >> 4) * 4);
      for (int tn = 0; tn < 4; ++tn) {
        int n = nBase + wn + tn * 16 + (lane & 15);
        for (int r = 0; r < 4; ++r) {
          float v = fmaxf(acc[tm][tn][r] + bias[tn], 0.0f);
          outp[(size_t)(mBase + rb + r) * 512 + n] = v;
        }
      }
    }
  }
}

// ---------------------------------------------------------------------------
extern "C" void kernel_launch(void* const* d_in, const int* in_sizes, int n_in,
                              void* d_out, int out_size, void* d_ws, size_t ws_size,
                              hipStream_t stream) {
  (void)in_sizes; (void)n_in; (void)out_size; (void)ws_size;

  const float* x     = (const float*)d_in[0];
  const int*   adj   = (const int*)d_in[1];
  const float* Wself = (const float*)d_in[2];
  const float* bself = (const float*)d_in[3];
  const float* Wnb   = (const float*)d_in[4];
  const float* bnb   = (const float*)d_in[5];
  const float* Wcomb = (const float*)d_in[6];
  const float* bcomb = (const float*)d_in[7];
  float* out = (float*)d_out;

  char* ws = (char*)d_ws;
  U16*   xT    = (U16*)(ws);                    // 8 MB  [512][8192] bf16
  U16*   xbf   = (U16*)(ws + 8388608);          // 8 MB  [8192][512] bf16
  U16*   aggp  = (U16*)(ws + 16777216);         // 8 MB  [8192][512] bf16
  U16*   Wt    = (U16*)(ws + 25165824);         // 1 MB  [512][1024] bf16
  float* cbias = (float*)(ws + 26214400);       // 2 KB  [512] fp32

#define ARGS(P) (P), x, adj, Wself, bself, Wnb, bnb, Wcomb, bcomb, xT, xbf, aggp, Wt, cbias, out
  GraphSAGELayer_773094114149_kernel<<<dim3(8, 128), 256, 0, stream>>>(ARGS(0));
  GraphSAGELayer_773094114149_kernel<<<dim3(258),    256, 0, stream>>>(ARGS(1));
  GraphSAGELayer_773094114149_kernel<<<dim3(4, 128), 256, 0, stream>>>(ARGS(2));
  GraphSAGELayer_773094114149_kernel<<<dim3(4, 128), 256, 0, stream>>>(ARGS(3));
#undef ARGS
}